// Round 5
// baseline (219.137 us; speedup 1.0000x reference)
//
#include <hip/hip_runtime.h>
#include <hip/hip_bf16.h>
#include <math.h>

#define NSENT 65536
#define NBAGS 4096
#define DIM 768
#define D4 192            // DIM/4
#define FLATC 53
#define CPAD 64           // padded class count for probs MFMA
#define GCLS 96           // padded global class count (95 real + 1 zero)
#define KTOT 2304         // 3*DIM
#define K4 576            // KTOT/4
#define CHUNK 512
#define MROWS 128         // sentence rows per logit_gemm block

typedef short bf16x8 __attribute__((ext_vector_type(8)));
typedef float f32x4 __attribute__((ext_vector_type(4)));

__device__ __forceinline__ float wsum(float v) {
#pragma unroll
  for (int o = 32; o; o >>= 1) v += __shfl_xor(v, o);
  return v;
}
__device__ __forceinline__ float wmax(float v) {
#pragma unroll
  for (int o = 32; o; o >>= 1) v = fmaxf(v, __shfl_xor(v, o));
  return v;
}
// f32 -> bf16 RNE via HIP intrinsic (compiles to v_cvt_pk_bf16_f32 on gfx950)
__device__ __forceinline__ unsigned short f2bf(float f) {
  union { __hip_bfloat16 b; unsigned short s; } cv;
  cv.b = __float2bfloat16(f);
  return cv.s;
}
__device__ __forceinline__ bf16x8 cvt8(float4 lo, float4 hi) {
  union { bf16x8 v; unsigned short s[8]; } u;
  u.s[0] = f2bf(lo.x); u.s[1] = f2bf(lo.y); u.s[2] = f2bf(lo.z); u.s[3] = f2bf(lo.w);
  u.s[4] = f2bf(hi.x); u.s[5] = f2bf(hi.y); u.s[6] = f2bf(hi.z); u.s[7] = f2bf(hi.w);
  return u.v;
}

// ---- K1: convert aw -> bf16 [96][768] (row 95 zero) and rw -> bf16 [64][2304]
__global__ __launch_bounds__(256) void cvt_weights(
    const float* __restrict__ aw, const float* __restrict__ rw,
    unsigned short* __restrict__ aw16, unsigned short* __restrict__ rw16) {
  const int idx = blockIdx.x * 256 + threadIdx.x;
  const int NAW = GCLS * DIM;
  if (idx < NAW) {
    const int row = idx / DIM;
    aw16[idx] = f2bf(row < 95 ? aw[idx] : 0.f);
  } else if (idx < NAW + CPAD * KTOT) {
    const int j = idx - NAW;
    const int row = j / KTOT;
    rw16[j] = f2bf(row < FLATC ? rw[j] : 0.f);
  }
}

// ---- K2: L[n][c] = x[n,:] . aw[c,:] for ALL classes, via bf16 MFMA ----
// Block = 128 sentence-rows x 96 classes; 4 waves, wave = 32 rows (2 tiles).
// x read once (f32, converted in-register); aw16 L2-resident. No LDS.
__global__ __launch_bounds__(256) void logit_gemm(
    const float* __restrict__ x, const unsigned short* __restrict__ aw16,
    float* __restrict__ L) {
  const int wv = threadIdx.x >> 6;
  const int lane = threadIdx.x & 63;
  const int r = lane & 15;
  const int kg = lane >> 4;
  const int m0 = blockIdx.x * MROWS + wv * 32;

  f32x4 acc[2][6];
#pragma unroll
  for (int t = 0; t < 2; t++)
#pragma unroll
    for (int ct = 0; ct < 6; ct++) acc[t][ct] = (f32x4){0.f, 0.f, 0.f, 0.f};

  // lane's A-rows: m0 + r and m0 + 16 + r; k-slice starts at kg*8 floats
  const float4* xp0 = (const float4*)(x + (size_t)(m0 + r) * DIM) + kg * 2;
  const float4* xp1 = (const float4*)(x + (size_t)(m0 + 16 + r) * DIM) + kg * 2;
  const unsigned short* bwp = aw16 + (size_t)r * DIM + kg * 8;

  for (int k = 0; k < DIM; k += 32) {
    const int f4 = k >> 2;  // float4 offset for this k-step
    const bf16x8 a0 = cvt8(xp0[f4], xp0[f4 + 1]);
    const bf16x8 a1 = cvt8(xp1[f4], xp1[f4 + 1]);
#pragma unroll
    for (int ct = 0; ct < 6; ct++) {
      const bf16x8 b = *(const bf16x8*)(bwp + (size_t)ct * 16 * DIM + k);
      acc[0][ct] = __builtin_amdgcn_mfma_f32_16x16x32_bf16(a0, b, acc[0][ct], 0, 0, 0);
      acc[1][ct] = __builtin_amdgcn_mfma_f32_16x16x32_bf16(a1, b, acc[1][ct], 0, 0, 0);
    }
  }

  // D mapping (same convention as passing probs_mfma):
  // row = tile*16 + kg*4 + reg, col = ct*16 + r
#pragma unroll
  for (int t = 0; t < 2; t++)
#pragma unroll
    for (int ct = 0; ct < 6; ct++)
#pragma unroll
      for (int reg = 0; reg < 4; reg++)
        L[(size_t)(m0 + t * 16 + kg * 4 + reg) * GCLS + ct * 16 + r] =
            acc[t][ct][reg];
}

// ---- K3: per-bag softmax + weighted sum. Gathers 3 logits/sentence from L.
__global__ __launch_bounds__(192) void bag_sum(
    const float* __restrict__ x, const float* __restrict__ L,
    const int* __restrict__ q, const int* __restrict__ scope,
    float* __restrict__ out, unsigned short* __restrict__ lt16) {
  const int b = blockIdx.x;
  const int s0 = scope[b];
  const int s1 = scope[b + 1];
  const int len = s1 - s0;
  const int tid = threadIdx.x;
  const int wave = tid >> 6;
  const int lane = tid & 63;

  __shared__ float lg[CHUNK][3];
  __shared__ float sm[3], se[3];

  float m[3] = {-INFINITY, -INFINITY, -INFINITY};
  float dsum[3] = {0.f, 0.f, 0.f};
  float4 acc[3];
#pragma unroll
  for (int l = 0; l < 3; l++) acc[l] = make_float4(0.f, 0.f, 0.f, 0.f);

  const float4* __restrict__ X4 = (const float4*)x;

  for (int cs = 0; cs < len; cs += CHUNK) {
    const int clen = min(CHUNK, len - cs);

    // gather logits for this chunk: lg[i][l] = L[n][q[n][l]]
    for (int idx = tid; idx < 3 * clen; idx += 192) {
      const int i = idx / 3;
      const int l = idx - 3 * i;
      const int n = s0 + cs + i;
      ((float*)lg)[idx] = L[(size_t)n * GCLS + q[3 * n + l]];
    }
    __syncthreads();

    // per-layer chunk max / exp / sum (wave w handles layer w)
    {
      const int l = wave;
      float cm = -INFINITY;
      for (int i = lane; i < clen; i += 64) cm = fmaxf(cm, lg[i][l]);
      cm = wmax(cm);
      const float mn = fmaxf(m[l], cm);
      float es = 0.f;
      for (int i = lane; i < clen; i += 64) {
        const float e = __expf(lg[i][l] - mn);
        es += e;
        lg[i][l] = e;  // unnormalized weight
      }
      es = wsum(es);
      if (lane == 0) { sm[l] = mn; se[l] = es; }
    }
    __syncthreads();

#pragma unroll
    for (int l = 0; l < 3; l++) {
      const float mn = sm[l];
      const float sc = __expf(m[l] - mn);  // exp(-inf)=0 first chunk
      m[l] = mn;
      dsum[l] = dsum[l] * sc + se[l];
      acc[l].x *= sc; acc[l].y *= sc; acc[l].z *= sc; acc[l].w *= sc;
    }

    // weighted accumulation, 4-sentence unroll; thread owns one float4 col
    {
      int i = 0;
      for (; i + 4 <= clen; i += 4) {
        float4 xv[4];
        float w0[4], w1[4], w2[4];
#pragma unroll
        for (int j = 0; j < 4; j++) {
          xv[j] = X4[(size_t)(s0 + cs + i + j) * D4 + tid];
          w0[j] = lg[i + j][0];
          w1[j] = lg[i + j][1];
          w2[j] = lg[i + j][2];
        }
#pragma unroll
        for (int j = 0; j < 4; j++) {
          acc[0].x += w0[j] * xv[j].x; acc[0].y += w0[j] * xv[j].y;
          acc[0].z += w0[j] * xv[j].z; acc[0].w += w0[j] * xv[j].w;
          acc[1].x += w1[j] * xv[j].x; acc[1].y += w1[j] * xv[j].y;
          acc[1].z += w1[j] * xv[j].z; acc[1].w += w1[j] * xv[j].w;
          acc[2].x += w2[j] * xv[j].x; acc[2].y += w2[j] * xv[j].y;
          acc[2].z += w2[j] * xv[j].z; acc[2].w += w2[j] * xv[j].w;
        }
      }
      for (; i < clen; i++) {
        const float a0 = lg[i][0], a1 = lg[i][1], a2 = lg[i][2];
        const float4 xv = X4[(size_t)(s0 + cs + i) * D4 + tid];
        acc[0].x += a0 * xv.x; acc[0].y += a0 * xv.y; acc[0].z += a0 * xv.z; acc[0].w += a0 * xv.w;
        acc[1].x += a1 * xv.x; acc[1].y += a1 * xv.y; acc[1].z += a1 * xv.z; acc[1].w += a1 * xv.w;
        acc[2].x += a2 * xv.x; acc[2].y += a2 * xv.y; acc[2].z += a2 * xv.z; acc[2].w += a2 * xv.w;
      }
    }
    __syncthreads();
  }

  // finalize: normalize, write both f32 layouts + bf16 copy for probs GEMM
  float4* o0 = (float4*)out;                              // stack [3][B][D]
  float4* o1 = (float4*)(out + (size_t)3 * NBAGS * DIM);  // lt [B][3*D]
  ushort4* l16 = (ushort4*)(lt16 + (size_t)b * KTOT);
#pragma unroll
  for (int l = 0; l < 3; l++) {
    const float inv = (dsum[l] > 0.f) ? (1.f / dsum[l]) : 0.f;
    float4 v = acc[l];
    v.x *= inv; v.y *= inv; v.z *= inv; v.w *= inv;
    o0[((size_t)l * NBAGS + b) * D4 + tid] = v;
    o1[(size_t)b * K4 + l * D4 + tid] = v;
    ushort4 h;
    h.x = f2bf(v.x); h.y = f2bf(v.y); h.z = f2bf(v.z); h.w = f2bf(v.w);
    l16[l * D4 + tid] = h;
  }
}

// ---- K4: probs = lt @ rw^T + bias via bf16 MFMA (64 bags x 64 classes) ----
__global__ __launch_bounds__(256) void probs_mfma(
    const unsigned short* __restrict__ lt16,
    const unsigned short* __restrict__ rw16,
    const float* __restrict__ bias, float* __restrict__ outp) {
  const int wv = threadIdx.x >> 6;
  const int lane = threadIdx.x & 63;
  const int r = lane & 15;
  const int kg = lane >> 4;
  const int bagbase = blockIdx.x * 64 + wv * 16;

  f32x4 acc[4];
#pragma unroll
  for (int ct = 0; ct < 4; ct++) acc[ct] = (f32x4){0.f, 0.f, 0.f, 0.f};

  const unsigned short* ap = lt16 + (size_t)(bagbase + r) * KTOT + kg * 8;
  const unsigned short* bp[4];
#pragma unroll
  for (int ct = 0; ct < 4; ct++)
    bp[ct] = rw16 + (size_t)(ct * 16 + r) * KTOT + kg * 8;

  for (int k = 0; k < KTOT; k += 32) {
    const bf16x8 a = *(const bf16x8*)(ap + k);
#pragma unroll
    for (int ct = 0; ct < 4; ct++) {
      const bf16x8 bb = *(const bf16x8*)(bp[ct] + k);
      acc[ct] = __builtin_amdgcn_mfma_f32_16x16x32_bf16(a, bb, acc[ct], 0, 0, 0);
    }
  }

#pragma unroll
  for (int ct = 0; ct < 4; ct++) {
    const int col = ct * 16 + r;
    if (col < FLATC) {
      const float bv = bias[col];
#pragma unroll
      for (int reg = 0; reg < 4; reg++) {
        const int bag = bagbase + kg * 4 + reg;
        outp[(size_t)bag * FLATC + col] = acc[ct][reg] + bv;
      }
    }
  }
}

extern "C" void kernel_launch(void* const* d_in, const int* in_sizes, int n_in,
                              void* d_out, int out_size, void* d_ws,
                              size_t ws_size, hipStream_t stream) {
  const float* x = (const float*)d_in[0];
  const int* aq = (const int*)d_in[1];
  const int* scope = (const int*)d_in[2];
  const float* aw = (const float*)d_in[3];
  const float* rw = (const float*)d_in[4];
  const float* bias = (const float*)d_in[5];
  float* out = (float*)d_out;

  unsigned short* lt16 = (unsigned short*)d_ws;           // 4096*2304 bf16
  unsigned short* rw16 = lt16 + (size_t)NBAGS * KTOT;     // 64*2304 bf16
  unsigned short* aw16 = rw16 + (size_t)CPAD * KTOT;      // 96*768 bf16
  float* L = (float*)(aw16 + (size_t)GCLS * DIM);         // 65536*96 f32

  const int ncvt = GCLS * DIM + CPAD * KTOT;
  hipLaunchKernelGGL(cvt_weights, dim3((ncvt + 255) / 256), dim3(256), 0,
                     stream, aw, rw, aw16, rw16);
  hipLaunchKernelGGL(logit_gemm, dim3(NSENT / MROWS), dim3(256), 0, stream, x,
                     aw16, L);
  hipLaunchKernelGGL(bag_sum, dim3(NBAGS), dim3(192), 0, stream, x, L, aq,
                     scope, out, lt16);

  float* probs = out + (size_t)3 * NBAGS * DIM + (size_t)NBAGS * KTOT;
  hipLaunchKernelGGL(probs_mfma, dim3(NBAGS / 64), dim3(256), 0, stream, lt16,
                     rw16, bias, probs);
}